// Round 1
// baseline (169.332 us; speedup 1.0000x reference)
//
#include <hip/hip_runtime.h>
#include <stdint.h>

using f16 = _Float16;

typedef _Float16 f16x8 __attribute__((ext_vector_type(8)));
typedef float f32x4 __attribute__((ext_vector_type(4)));
typedef float f32x16 __attribute__((ext_vector_type(16)));

#define LOG2E 1.44269504088896340736f

__device__ __forceinline__ f16 f2h(float f) { return (f16)f; }  // RNE

#if __has_builtin(__builtin_amdgcn_exp2f)
__device__ __forceinline__ float fexp2(float x) { return __builtin_amdgcn_exp2f(x); }
#else
__device__ __forceinline__ float fexp2(float x) { return exp2f(x); }
#endif

__device__ __forceinline__ f16x8 cvt8(const float* p) {
  const float4 a = *(const float4*)p;
  const float4 b = *(const float4*)(p + 4);
  f16x8 r;
  r[0] = (f16)a.x; r[1] = (f16)a.y; r[2] = (f16)a.z; r[3] = (f16)a.w;
  r[4] = (f16)b.x; r[5] = (f16)b.y; r[6] = (f16)b.z; r[7] = (f16)b.w;
  return r;
}

// B=4, C=64, N=4096.  Global in/out FP32; internal tensor-core path FP16.
// ws layout (bytes):
//   0     qa  f16 [4][4096][64]      (2 MB)  q*log2e, position-major
//   2 MB  ka2 f16 [4][8][4096][8]    (2 MB)  K channel-chunked: [b][c8][key][8c]
//   4 MB  va3 f16 [4][512][64][8]    (2 MB)  V key-chunked:     [b][k8][c][8k]
//   6 MB  y0  f32 [4][64][4096]      (4 MB)  gamma*attn_out, pre-BN
//   10 MB stats: gs1[64] | gs2[64]   (zeroed by pre block 0)

// ---------------------------------------------------------------------------
// pre: conv1d q/k over channels, v = vw@x+vb via MFMA.  (unchanged except the
// va3 layout: 8-key chunks so attn PV B-frags are single b128 loads)
// ---------------------------------------------------------------------------
__global__ __launch_bounds__(256, 2) void pam_pre(
    const float* __restrict__ x, const float* __restrict__ qw,
    const float* __restrict__ kw, const float* __restrict__ vw,
    const float* __restrict__ vb,
    f16* __restrict__ qa, f16* __restrict__ ka2, f16* __restrict__ va3,
    float* __restrict__ gz)
{
  __shared__ alignas(16) f16 xt[16 * 72];   // xt[n][c] f16, row stride 72
  const int tid = threadIdx.x;
  const int b = blockIdx.x >> 8;
  const int n0 = (blockIdx.x & 255) << 4;
  const int lane = tid & 63;
  const int wv = tid >> 6;
  const int quad = lane >> 4, l15 = lane & 15;

  if (blockIdx.x == 0 && tid < 128) gz[tid] = 0.f;   // gs1|gs2 zero-init

  // stage x[b][c][n0:+16] (fp32) transposed into xt[n][c] (f16)
  {
    const int c = tid >> 2;
    const int j0 = (tid & 3) << 2;
    const float4 v0 = *(const float4*)(x + ((size_t)(b * 64 + c) << 12) + n0 + j0);
    xt[(j0 + 0) * 72 + c] = f2h(v0.x);
    xt[(j0 + 1) * 72 + c] = f2h(v0.y);
    xt[(j0 + 2) * 72 + c] = f2h(v0.z);
    xt[(j0 + 3) * 72 + c] = f2h(v0.w);
  }
  __syncthreads();

  // conv over channel axis (SAME, zero pad)
  const float qw0 = qw[0], qw1 = qw[1], qw2 = qw[2];
  const float kw0 = kw[0], kw1 = kw[1], kw2 = kw[2];
  for (int p = 0; p < 4; ++p) {
    const int c = lane;
    const int jr = (p << 2) + wv;
    const int n = n0 + jr;
    const float xm = (c > 0) ? (float)xt[jr * 72 + c - 1] : 0.f;
    const float x0 = (float)xt[jr * 72 + c];
    const float xp = (c < 63) ? (float)xt[jr * 72 + c + 1] : 0.f;
    const float qv = (qw0 * xm + qw1 * x0 + qw2 * xp) * LOG2E;  // log2-domain
    const float kv = kw0 * xm + kw1 * x0 + kw2 * xp;
    qa[((size_t)((b << 12) + n) << 6) + c] = f2h(qv);
    ka2[((size_t)(b * 8 + (c >> 3)) << 15) + (n << 3) + (c & 7)] = f2h(kv);
  }

  // v[c][n] = vw @ x + vb via mfma (wave wv -> c rows [16wv,+16))
  {
    const f16x8 a0 = cvt8(vw + (wv * 16 + l15) * 64 + quad * 8);
    const f16x8 a1 = cvt8(vw + (wv * 16 + l15) * 64 + quad * 8 + 32);
    const f16x8 b0 = *(const f16x8*)&xt[l15 * 72 + quad * 8];
    const f16x8 b1 = *(const f16x8*)&xt[l15 * 72 + quad * 8 + 32];
    f32x4 z = {0.f, 0.f, 0.f, 0.f};
    z = __builtin_amdgcn_mfma_f32_16x16x32_f16(a0, b0, z, 0, 0, 0);
    z = __builtin_amdgcn_mfma_f32_16x16x32_f16(a1, b1, z, 0, 0, 0);
    const int cobase = wv * 16 + quad * 4;
    for (int r = 0; r < 4; ++r) {
      const int co = cobase + r;
      const int n = n0 + l15;
      const float val = z[r] + vb[co];
      // va3[b][n>>3][co][n&7]
      va3[(((size_t)(b * 512 + (n >> 3))) << 9) + (co << 3) + (n & 7)] = f2h(val);
    }
  }
}

// ---------------------------------------------------------------------------
// attention v17: barrier-free streaming redesign.
//  - grid 256 x 1024 thr (1 block/CU, 16 waves = 4/SIMD).  Block = 2 q-groups
//    of 32 queries x 8-way key split; every wave owns an independent online-
//    softmax stream over 512 keys (16 iters x 32 keys).  ZERO __syncthreads
//    in the main loop: K/V fragments stream L2->VGPR via plain global loads,
//    per-wave waitcnt only, waves self-pace (no convoy, no vmcnt(0) drain).
//  - all MFMAs are 32x32x16 f16.  QK^T computes S^T with K rows loaded in
//    bit2<->bit3-swapped order g(q); with the 32x32 C/D layout
//    (row=(reg&3)+8*(reg>>2)+4*hi) this makes reg p of lane(hi) hold key
//    (p>>3)*16 + hi*8 + (p&7)  ==  exactly the A/B-frag k-order PV needs,
//    so P goes softmax->PV with no cross-lane traffic at all.
//  - defer-max (THR=8): O-rescale only when a tile's max beats m by >8.
//  - XCD-affine: blockIdx%8 -> batch slot>>1, pins 1 MB K+V per XCD L2.
//  - LDS only for the final 8-way m-aware merge + BN epilogue.
// ---------------------------------------------------------------------------
__global__ __launch_bounds__(1024, 4) void pam_attn(
    const f16* __restrict__ qa, const f16* __restrict__ ka2,
    const f16* __restrict__ va3, const float* __restrict__ gam,
    float* __restrict__ y0, float* __restrict__ gs1, float* __restrict__ gs2)
{
  __shared__ alignas(16) float ldsO[2][64][32];          // 16 KB  O^T partial sums
  __shared__ float ldsM[2][8][32], ldsL[2][8][32];       //  4 KB  per-wave m / l
  __shared__ float ldsInv[2][32];                        // 256 B  1/denominator

  const int tid = threadIdx.x;
  const int lane = tid & 63, wv = tid >> 6;
  const int qg = wv >> 3, ks = wv & 7;                   // q-group, key-slice
  const int q = lane & 31, hi = lane >> 5;
  const int slot = (int)blockIdx.x & 7, tt = (int)blockIdx.x >> 3;
  const int b = slot >> 1;                               // 2 XCDs per batch
  const int qb0 = ((tt << 1) | (slot & 1)) << 6;         // block's 64-query base
  const int qbase = qb0 + (qg << 5);

  { // zero the merge accumulator (completes before first __syncthreads)
    float* z0 = (float*)ldsO;
    for (int i = tid; i < 2 * 64 * 32; i += 1024) z0[i] = 0.f;
  }

  // Q fragments: 32 q x 64 c per wave (B-operand, col=q=lane&31, k=hi*8+j)
  f16x8 bq0, bq1, bq2, bq3;
  {
    const f16* qp = qa + (((size_t)((b << 12) + qbase + q)) << 6) + (hi << 3);
    bq0 = *(const f16x8*)(qp);
    bq1 = *(const f16x8*)(qp + 16);
    bq2 = *(const f16x8*)(qp + 32);
    bq3 = *(const f16x8*)(qp + 48);
  }

  // K row permutation: swap bits 2<->3 of the S^T-row index
  const int gq = (q & 0x13) | ((q & 4) << 1) | ((q & 8) >> 1);
  // K frag base: ka2[b][c8=2s+hi][key = ks*512 + kt*32 + g(q)][8c]
  const f16* kp0 = ka2 + (((size_t)(b * 8 + hi)) << 15) + (ks << 12) + (gq << 3);
  // V frag base: va3[b][k8 = ks*64 + kt*4 + kc*2 + hi][c = ct*32 + q][8k]
  const f16* vp0 = va3 + (((size_t)(b * 512 + ks * 64 + hi)) << 9) + (q << 3);

  f32x16 oc0 = {}, oc1 = {};        // O^T[c][q], c-halves 0..31 / 32..63
  float m = -1e30f, lp = 0.f;

  // prefetch K for iter 0 (s-chunks are 65536-elem apart)
  f16x8 k0 = *(const f16x8*)(kp0);
  f16x8 k1 = *(const f16x8*)(kp0 + 65536);
  f16x8 k2 = *(const f16x8*)(kp0 + 131072);
  f16x8 k3 = *(const f16x8*)(kp0 + 196608);

#pragma unroll 2
  for (int kt = 0; kt < 16; ++kt) {
    // V loads for this iter: latency covered by QK^T + softmax below
    const f16* vp = vp0 + (kt << 11);
    const f16x8 v00 = *(const f16x8*)(vp);          // kc0, c 0..31
    const f16x8 v01 = *(const f16x8*)(vp + 256);    // kc0, c 32..63
    const f16x8 v10 = *(const f16x8*)(vp + 1024);   // kc1, c 0..31
    const f16x8 v11 = *(const f16x8*)(vp + 1280);   // kc1, c 32..63

    // S^T[32 key][32 q], K-reduction over 64 channels
    f32x16 z = {};
    __builtin_amdgcn_s_setprio(1);
    z = __builtin_amdgcn_mfma_f32_32x32x16_f16(k0, bq0, z, 0, 0, 0);
    z = __builtin_amdgcn_mfma_f32_32x32x16_f16(k1, bq1, z, 0, 0, 0);
    z = __builtin_amdgcn_mfma_f32_32x32x16_f16(k2, bq2, z, 0, 0, 0);
    z = __builtin_amdgcn_mfma_f32_32x32x16_f16(k3, bq3, z, 0, 0, 0);
    __builtin_amdgcn_s_setprio(0);

    // prefetch K for next iter into the same regs (WAR resolved by compiler)
    if (kt < 15) {
      const f16* kp = kp0 + ((kt + 1) << 8);
      k0 = *(const f16x8*)(kp);
      k1 = *(const f16x8*)(kp + 65536);
      k2 = *(const f16x8*)(kp + 131072);
      k3 = *(const f16x8*)(kp + 196608);
    }

    // online softmax: lane-local per query, one shfl for the hi-half
    float t0 = fmaxf(fmaxf(z[0], z[1]), fmaxf(z[2], z[3]));
    float t1 = fmaxf(fmaxf(z[4], z[5]), fmaxf(z[6], z[7]));
    float t2 = fmaxf(fmaxf(z[8], z[9]), fmaxf(z[10], z[11]));
    float t3 = fmaxf(fmaxf(z[12], z[13]), fmaxf(z[14], z[15]));
    float tmax = fmaxf(fmaxf(t0, t1), fmaxf(t2, t3));
    tmax = fmaxf(tmax, __shfl_xor(tmax, 32, 64));
    const bool need = !__all(tmax <= m + 8.f);      // defer-max, THR=8
    const float mn = need ? fmaxf(m, tmax) : m;

    float p[16];
#pragma unroll
    for (int j = 0; j < 16; ++j) p[j] = fexp2(z[j] - mn);
    float s0 = (p[0] + p[1]) + (p[2] + p[3]);
    float s1 = (p[4] + p[5]) + (p[6] + p[7]);
    float s2 = (p[8] + p[9]) + (p[10] + p[11]);
    float s3 = (p[12] + p[13]) + (p[14] + p[15]);
    const float ts = (s0 + s1) + (s2 + s3);

    f16x8 pa0, pa1;   // P frags: reg order == PV k order (by construction)
#pragma unroll
    for (int j = 0; j < 8; ++j) { pa0[j] = f2h(p[j]); pa1[j] = f2h(p[j + 8]); }

    if (need) {
      const float al = fexp2(m - mn);
      lp = lp * al + ts;
      m = mn;
#pragma unroll
      for (int j = 0; j < 16; ++j) { oc0[j] *= al; oc1[j] *= al; }
    } else {
      lp += ts;
    }

    // O^T += V * P^T  (A = V[32c x 16k], B = P^T[16k x 32q])
    __builtin_amdgcn_s_setprio(1);
    oc0 = __builtin_amdgcn_mfma_f32_32x32x16_f16(v00, pa0, oc0, 0, 0, 0);
    oc0 = __builtin_amdgcn_mfma_f32_32x32x16_f16(v10, pa1, oc0, 0, 0, 0);
    oc1 = __builtin_amdgcn_mfma_f32_32x32x16_f16(v01, pa0, oc1, 0, 0, 0);
    oc1 = __builtin_amdgcn_mfma_f32_32x32x16_f16(v11, pa1, oc1, 0, 0, 0);
    __builtin_amdgcn_s_setprio(0);
  }

  // publish per-wave online state (m is hi-symmetric; lp summed across hi)
  lp += __shfl_xor(lp, 32, 64);
  if (hi == 0) { ldsM[qg][ks][q] = m; ldsL[qg][ks][q] = lp; }
  __syncthreads();

  // per-query global max + denom over the 8 key-slices
  float M = ldsM[qg][0][q];
#pragma unroll
  for (int k = 1; k < 8; ++k) M = fmaxf(M, ldsM[qg][k][q]);
  float lt = 0.f;
#pragma unroll
  for (int k = 0; k < 8; ++k) lt += ldsL[qg][k][q] * fexp2(ldsM[qg][k][q] - M);
  if (ks == 0 && hi == 0) ldsInv[qg][q] = 1.f / lt;
  const float sc = fexp2(m - M);

  // m-aware merge: c = (t&3) + 8*(t>>2) + 4*hi (+32 for oc1), q = lane&31
#pragma unroll
  for (int t = 0; t < 16; ++t) {
    const int c0 = (t & 3) + ((t >> 2) << 3) + (hi << 2);
    atomicAdd(&ldsO[qg][c0][q], oc0[t] * sc);
    atomicAdd(&ldsO[qg][c0 + 32][q], oc1[t] * sc);
  }
  __syncthreads();

  // epilogue: y0[b][c][n] = gamma * O / l ; BN partial sums
  const float g = gam[0];
  {
    const int qg2 = tid >> 9;
    const int c = (tid >> 3) & 63;
    const int q0 = (tid & 7) << 2;
    const int nn = qb0 + (qg2 << 5) + q0;
    float4 v4;
    float* vp4 = &v4.x;
    float b1 = 0.f, b2 = 0.f;
#pragma unroll
    for (int r = 0; r < 4; ++r) {
      const float val = g * ldsO[qg2][c][q0 + r] * ldsInv[qg2][q0 + r];
      vp4[r] = val; b1 += val; b2 += val * val;
    }
    *(float4*)(y0 + (((size_t)(b * 64 + c)) << 12) + nn) = v4;
    b1 += __shfl_xor(b1, 1, 64); b2 += __shfl_xor(b2, 1, 64);
    b1 += __shfl_xor(b1, 2, 64); b2 += __shfl_xor(b2, 2, 64);
    b1 += __shfl_xor(b1, 4, 64); b2 += __shfl_xor(b2, 4, 64);
    if ((tid & 7) == 0) {
      atomicAdd(&gs1[c], b1);
      atomicAdd(&gs2[c], b2);
    }
  }
}

// ---------------------------------------------------------------------------
// apply: BN(scale/shift from gs1/gs2) + residual.
// ---------------------------------------------------------------------------
__global__ __launch_bounds__(256, 2) void pam_apply(
    const float* __restrict__ y0, const float* __restrict__ x,
    const float* __restrict__ gs1, const float* __restrict__ gs2,
    const float* __restrict__ bnw, const float* __restrict__ bnb,
    float* __restrict__ out)
{
  const int i = (blockIdx.x * 256 + threadIdx.x) << 2;   // 4 elems/thread
  const int c = (i >> 12) & 63;
  const float inv_n = 1.f / 16384.f;
  const float mean = gs1[c] * inv_n;
  const float var = fmaxf(gs2[c] * inv_n - mean * mean, 0.f);
  const float sc = bnw[c] * rsqrtf(var + 1e-5f);
  const float sh = bnb[c] - mean * sc;
  const float4 y = *(const float4*)(y0 + i);
  const float4 xv = *(const float4*)(x + i);
  float4 r;
  r.x = y.x * sc + sh + xv.x;
  r.y = y.y * sc + sh + xv.y;
  r.z = y.z * sc + sh + xv.z;
  r.w = y.w * sc + sh + xv.w;
  *(float4*)(out + i) = r;
}

// ---------------------------------------------------------------------------
extern "C" void kernel_launch(void* const* d_in, const int* in_sizes, int n_in,
                              void* d_out, int out_size, void* d_ws, size_t ws_size,
                              hipStream_t stream)
{
  (void)in_sizes; (void)n_in; (void)out_size; (void)ws_size;
  const float* x   = (const float*)d_in[0];
  const float* qw  = (const float*)d_in[1];
  const float* kw  = (const float*)d_in[2];
  const float* vw  = (const float*)d_in[3];
  const float* vb  = (const float*)d_in[4];
  const float* gam = (const float*)d_in[5];
  const float* bnw = (const float*)d_in[6];
  const float* bnb = (const float*)d_in[7];

  char* ws = (char*)d_ws;
  f16*   qa  = (f16*)(ws);
  f16*   ka2 = (f16*)(ws + (2u << 20));
  f16*   va3 = (f16*)(ws + (4u << 20));
  float* y0  = (float*)(ws + (6u << 20));
  float* gs1 = (float*)(ws + (10u << 20));          // 64 floats
  float* gs2 = (float*)(ws + (10u << 20) + 256);    // 64 floats (contiguous)

  pam_pre  <<<1024, 256, 0, stream>>>(x, qw, kw, vw, vb, qa, ka2, va3, gs1);
  pam_attn <<<256, 1024, 0, stream>>>(qa, ka2, va3, gam, y0, gs1, gs2);
  pam_apply<<<1024, 256, 0, stream>>>(y0, x, gs1, gs2, bnw, bnb, (float*)d_out);
}

// Round 2
// 149.749 us; speedup vs baseline: 1.1308x; 1.1308x over previous
//
#include <hip/hip_runtime.h>
#include <stdint.h>

using f16 = _Float16;

typedef _Float16 f16x8 __attribute__((ext_vector_type(8)));
typedef _Float16 f16x4 __attribute__((ext_vector_type(4)));
typedef float f32x4 __attribute__((ext_vector_type(4)));

#define LOG2E 1.44269504088896340736f

__device__ __forceinline__ f16 f2h(float f) { return (f16)f; }  // RNE

#if __has_builtin(__builtin_amdgcn_exp2f)
__device__ __forceinline__ float fexp2(float x) { return __builtin_amdgcn_exp2f(x); }
#else
__device__ __forceinline__ float fexp2(float x) { return exp2f(x); }
#endif

typedef __attribute__((address_space(1))) const uint32_t gu32;
typedef __attribute__((address_space(3))) uint32_t lu32;

__device__ __forceinline__ void dma16(const void* g, void* l) {
  // global->LDS DMA, 16 B/lane. Global source is PER-LANE (caller includes
  // lane*16B); LDS dest is wave-uniform base + lane*16 auto-stride.
  __builtin_amdgcn_global_load_lds((gu32*)g, (lu32*)l, 16, 0, 0);
}

__device__ __forceinline__ f16x8 cvt8(const float* p) {
  const float4 a = *(const float4*)p;
  const float4 b = *(const float4*)(p + 4);
  f16x8 r;
  r[0] = (f16)a.x; r[1] = (f16)a.y; r[2] = (f16)a.z; r[3] = (f16)a.w;
  r[4] = (f16)b.x; r[5] = (f16)b.y; r[6] = (f16)b.z; r[7] = (f16)b.w;
  return r;
}

// B=4, C=64, N=4096.  Global in/out FP32; internal tensor-core path FP16.
// ws layout (bytes):
//   0     qa  f16 [4][4096][64]      (2 MB)  q*log2e, position-major
//   2 MB  ka2 f16 [4][8][4096][8]    (2 MB)  K channel-chunked: [b][c8][key][8c]
//   4 MB  va3 f16 [4][512][64][8]    (2 MB)  V key-chunked:     [b][k8][c][8k]
//   6 MB  y0  f32 [4][64][4096]      (4 MB)  gamma*attn_out, pre-BN
//   10 MB stats: gs1[64] | gs2[64]   (zeroed by pre block 0)

// ---------------------------------------------------------------------------
// pre: conv1d q/k over channels, v = vw@x+vb via MFMA.
// ---------------------------------------------------------------------------
__global__ __launch_bounds__(256, 2) void pam_pre(
    const float* __restrict__ x, const float* __restrict__ qw,
    const float* __restrict__ kw, const float* __restrict__ vw,
    const float* __restrict__ vb,
    f16* __restrict__ qa, f16* __restrict__ ka2, f16* __restrict__ va3,
    float* __restrict__ gz)
{
  __shared__ alignas(16) f16 xt[16 * 72];   // xt[n][c] f16, row stride 72
  const int tid = threadIdx.x;
  const int b = blockIdx.x >> 8;
  const int n0 = (blockIdx.x & 255) << 4;
  const int lane = tid & 63;
  const int wv = tid >> 6;
  const int quad = lane >> 4, l15 = lane & 15;

  if (blockIdx.x == 0 && tid < 128) gz[tid] = 0.f;   // gs1|gs2 zero-init

  // stage x[b][c][n0:+16] (fp32) transposed into xt[n][c] (f16)
  {
    const int c = tid >> 2;
    const int j0 = (tid & 3) << 2;
    const float4 v0 = *(const float4*)(x + ((size_t)(b * 64 + c) << 12) + n0 + j0);
    xt[(j0 + 0) * 72 + c] = f2h(v0.x);
    xt[(j0 + 1) * 72 + c] = f2h(v0.y);
    xt[(j0 + 2) * 72 + c] = f2h(v0.z);
    xt[(j0 + 3) * 72 + c] = f2h(v0.w);
  }
  __syncthreads();

  // conv over channel axis (SAME, zero pad)
  const float qw0 = qw[0], qw1 = qw[1], qw2 = qw[2];
  const float kw0 = kw[0], kw1 = kw[1], kw2 = kw[2];
  for (int p = 0; p < 4; ++p) {
    const int c = lane;
    const int jr = (p << 2) + wv;
    const int n = n0 + jr;
    const float xm = (c > 0) ? (float)xt[jr * 72 + c - 1] : 0.f;
    const float x0 = (float)xt[jr * 72 + c];
    const float xp = (c < 63) ? (float)xt[jr * 72 + c + 1] : 0.f;
    const float qv = (qw0 * xm + qw1 * x0 + qw2 * xp) * LOG2E;  // log2-domain
    const float kv = kw0 * xm + kw1 * x0 + kw2 * xp;
    qa[((size_t)((b << 12) + n) << 6) + c] = f2h(qv);
    ka2[((size_t)(b * 8 + (c >> 3)) << 15) + (n << 3) + (c & 7)] = f2h(kv);
  }

  // v[c][n] = vw @ x + vb via mfma (wave wv -> c rows [16wv,+16))
  {
    const f16x8 a0 = cvt8(vw + (wv * 16 + l15) * 64 + quad * 8);
    const f16x8 a1 = cvt8(vw + (wv * 16 + l15) * 64 + quad * 8 + 32);
    const f16x8 b0 = *(const f16x8*)&xt[l15 * 72 + quad * 8];
    const f16x8 b1 = *(const f16x8*)&xt[l15 * 72 + quad * 8 + 32];
    f32x4 z = {0.f, 0.f, 0.f, 0.f};
    z = __builtin_amdgcn_mfma_f32_16x16x32_f16(a0, b0, z, 0, 0, 0);
    z = __builtin_amdgcn_mfma_f32_16x16x32_f16(a1, b1, z, 0, 0, 0);
    const int cobase = wv * 16 + quad * 4;
    for (int r = 0; r < 4; ++r) {
      const int co = cobase + r;
      const int n = n0 + l15;
      const float val = z[r] + vb[co];
      // va3[b][n>>3][co][n&7]
      va3[(((size_t)(b * 512 + (n >> 3))) << 9) + (co << 3) + (n & 7)] = f2h(val);
    }
  }
}

// ---------------------------------------------------------------------------
// attention v18 = v16 skeleton (DMA double-buffer, 1 barrier/iter, 512 thr,
// 2 blocks/CU) + surgical upgrades:
//  - O^T dataflow: PV computes O^T[c][q] = V * P^T with 16x16x32 (full-rate,
//    4 MFMAs/iter instead of 8 half-rate 16x16x16).
//  - K-row permutation at LDS read (key = (p>>2)*8 + t*4 + (p&3)): S^T output
//    registers land exactly in PV's B-frag k-order -> zero-shuffle P, single
//    f16x8 pack, no repack VALU.
//  - q lives in the MFMA column for both S^T and O^T -> online-softmax state
//    (m, lp, alpha) is lane-local; the 4-shuffle alpha broadcast is gone.
//  - defer-max (THR=8, log2-domain): skip the 16-mul O-rescale unless the
//    tile max beats m by >8; p bounded by 2^8, safe in f16.
// Waves = (qh 0..1 of 16q, ks 0..3 of 32 keys), 128-key tiles, 32 iters.
// ---------------------------------------------------------------------------
__global__ __launch_bounds__(512, 2) void pam_attn(
    const f16* __restrict__ qa, const f16* __restrict__ ka2,
    const f16* __restrict__ va3, const float* __restrict__ gam,
    float* __restrict__ y0, float* __restrict__ gs1, float* __restrict__ gs2)
{
  __shared__ alignas(16) f16 kbuf[2][8192];   // [c8][128key][8c], 16 KB each
  __shared__ alignas(16) f16 vbuf[2][8192];   // [16 k8][64 c][8 k], 16 KB each
  __shared__ float ldsO[32 * 65];             // [q][c], pad 65
  __shared__ float ldsM[4][32], ldsL[4][32], ldsMg[32], ldsInv[32];

  const int tid = threadIdx.x;
  const int wv = tid >> 6, lane = tid & 63;
  const int quad = lane >> 4, l15 = lane & 15;
  const int ks = wv & 3, qh = wv >> 2;
  const int b = blockIdx.x & 3;
  const int qb = blockIdx.x >> 2;          // 0..127
  const int qb0 = qb << 5;
  const int phase = qb & 31;               // anti-convoy rotation (32 tiles)

  for (int i = tid; i < 32 * 65; i += 512) ldsO[i] = 0.f;

  const int bn = b << 12;
  // Q fragments (B-operand: col=l15=q, k=quad*8+j over channels)
  f16x8 bq0, bq1;
  {
    const int q = qb0 + qh * 16 + l15;
    const f16* qp = qa + ((size_t)(bn + q) << 6) + quad * 8;
    bq0 = *(const f16x8*)qp;
    bq1 = *(const f16x8*)(qp + 32);
  }

  // staging bases (PER-LANE source: + lane*8 f16 = 16 B/lane).
  // K: wave wv stages c8-group wv (128 keys x 8c = 2 KB per tile).
  // V: wave wv stages k8-chunks {2wv, 2wv+1} (2 x 1 KB per tile).
  const f16* kg0 = ka2 + (((size_t)(b * 8 + wv)) << 15) + (lane << 3);
  const f16* vg0 = va3 + ((size_t)b << 18) + (wv << 10) + (lane << 3);

  f32x4 o[4] = {};                 // O^T: col=l15=q, row c = ct*16+quad*4+r
  float m = -1e30f, lp = 0.f;

  // stage tile 'phase' into buf 0
  dma16(kg0 + ((size_t)phase << 10),       kbuf[0] + (wv << 10));
  dma16(kg0 + ((size_t)phase << 10) + 512, kbuf[0] + (wv << 10) + 512);
  dma16(vg0 + ((size_t)phase << 13),       vbuf[0] + (wv << 10));
  dma16(vg0 + ((size_t)phase << 13) + 512, vbuf[0] + (wv << 10) + 512);
  __syncthreads();

  // K-row permutation: A-frag lane l15 loads key (l15>>2)*8 + t*4 + (l15&3)
  // so S^T output reg r of quad holds key quad*8 + t*4 + r == PV k-order.
  const int kperm = (ks << 5) + (((l15 >> 2) << 3) | (l15 & 3));
  const int koff0 = kperm << 3;            // ktile t=0
  const int koff1 = (kperm + 4) << 3;      // ktile t=1
  const int vbase = ((ks * 4 + quad) << 9) + (l15 << 3);

#pragma unroll 1
  for (int kt = 0; kt < 32; ++kt) {
    const int cur = kt & 1;
    {
      const int tn = (kt + 1 + phase) & 31;
      f16* kd = kbuf[cur ^ 1] + (wv << 10);
      f16* vd = vbuf[cur ^ 1] + (wv << 10);
      dma16(kg0 + ((size_t)tn << 10),       kd);
      dma16(kg0 + ((size_t)tn << 10) + 512, kd + 512);
      dma16(vg0 + ((size_t)tn << 13),       vd);
      dma16(vg0 + ((size_t)tn << 13) + 512, vd + 512);
    }

    const f16* kc = kbuf[cur];
    const f16* vc = vbuf[cur];
    const f16x8 ak00 = *(const f16x8*)(kc + (quad << 10) + koff0);
    const f16x8 ak01 = *(const f16x8*)(kc + ((4 + quad) << 10) + koff0);
    const f16x8 ak10 = *(const f16x8*)(kc + (quad << 10) + koff1);
    const f16x8 ak11 = *(const f16x8*)(kc + ((4 + quad) << 10) + koff1);

    // S^T[32 key (permuted)][16 q], contraction over 64 channels
    f32x4 z0, z1;
    {
      f32x4 z = {0.f, 0.f, 0.f, 0.f};
      z = __builtin_amdgcn_mfma_f32_16x16x32_f16(ak00, bq0, z, 0, 0, 0);
      z0 = __builtin_amdgcn_mfma_f32_16x16x32_f16(ak01, bq1, z, 0, 0, 0);
    }
    {
      f32x4 z = {0.f, 0.f, 0.f, 0.f};
      z = __builtin_amdgcn_mfma_f32_16x16x32_f16(ak10, bq0, z, 0, 0, 0);
      s1_label:
      z1 = __builtin_amdgcn_mfma_f32_16x16x32_f16(ak11, bq1, z, 0, 0, 0);
    }

    // online softmax: lane holds keys quad*8+{0..7} for query q=l15
    float tmax = fmaxf(fmaxf(fmaxf(z0[0], z0[1]), fmaxf(z0[2], z0[3])),
                       fmaxf(fmaxf(z1[0], z1[1]), fmaxf(z1[2], z1[3])));
    tmax = fmaxf(tmax, __shfl_xor(tmax, 16, 64));
    tmax = fmaxf(tmax, __shfl_xor(tmax, 32, 64));
    const bool need = !__all(tmax <= m + 8.f);    // defer-max, THR=8
    const float mn = need ? fmaxf(m, tmax) : m;

    const float p0 = fexp2(z0[0] - mn);
    const float p1 = fexp2(z0[1] - mn);
    const float p2 = fexp2(z0[2] - mn);
    const float p3 = fexp2(z0[3] - mn);
    const float p4 = fexp2(z1[0] - mn);
    const float p5 = fexp2(z1[1] - mn);
    const float p6 = fexp2(z1[2] - mn);
    const float p7 = fexp2(z1[3] - mn);
    const float ts = ((p0 + p1) + (p2 + p3)) + ((p4 + p5) + (p6 + p7));

    f16x8 pa;   // P^T B-frag: k-order == reg order (by K permutation)
    pa[0] = f2h(p0); pa[1] = f2h(p1); pa[2] = f2h(p2); pa[3] = f2h(p3);
    pa[4] = f2h(p4); pa[5] = f2h(p5); pa[6] = f2h(p6); pa[7] = f2h(p7);

    if (need) {
      const float al = fexp2(m - mn);   // lane-local (q in column)
      lp = lp * al + ts;
      m = mn;
#pragma unroll
      for (int ct = 0; ct < 4; ++ct)
        for (int r = 0; r < 4; ++r) o[ct][r] *= al;
    } else {
      lp += ts;
    }

    // O^T += V * P^T : one K=32 MFMA per 16-channel tile
#pragma unroll
    for (int ct = 0; ct < 4; ++ct) {
      const f16x8 av = *(const f16x8*)(vc + vbase + ct * 128);
      o[ct] = __builtin_amdgcn_mfma_f32_16x16x32_f16(av, pa, o[ct], 0, 0, 0);
    }
    __syncthreads();   // DMA landed + all waves done with buffers
  }

  // publish per-wave online state (m quad-uniform; lp reduced across quads)
  {
    float v = lp;
    v += __shfl_xor(v, 16, 64);
    v += __shfl_xor(v, 32, 64);
    if (quad == 0) {
      ldsM[ks][qh * 16 + l15] = m;
      ldsL[ks][qh * 16 + l15] = v;
    }
  }
  __syncthreads();

  // per-query global max + denom (4 key-slices)
  if (tid < 32) {
    const float M = fmaxf(fmaxf(ldsM[0][tid], ldsM[1][tid]),
                          fmaxf(ldsM[2][tid], ldsM[3][tid]));
    const float lt = ldsL[0][tid] * fexp2(ldsM[0][tid] - M) +
                     ldsL[1][tid] * fexp2(ldsM[1][tid] - M) +
                     ldsL[2][tid] * fexp2(ldsM[2][tid] - M) +
                     ldsL[3][tid] * fexp2(ldsM[3][tid] - M);
    ldsMg[tid] = M;
    ldsInv[tid] = 1.f / lt;
  }
  __syncthreads();

  // m-aware merge of partial O^T across the 4 key-split waves (sc lane-local)
  {
    const int q = qh * 16 + l15;
    const float sc = fexp2(m - ldsMg[q]);
#pragma unroll
    for (int ct = 0; ct < 4; ++ct)
      for (int r = 0; r < 4; ++r)
        atomicAdd(&ldsO[q * 65 + ct * 16 + quad * 4 + r], o[ct][r] * sc);
  }
  __syncthreads();

  // epilogue: y0[b][c][n] = gamma * O / l ; BN partial sums
  const float g = gam[0];
  {
    const int c = tid >> 3;              // 0..63
    const int q0 = (tid & 7) << 2;       // 0..28
    float4 v4;
    float* vp = &v4.x;
    float s1 = 0.f, s2 = 0.f;
    for (int r = 0; r < 4; ++r) {
      const float val = g * ldsO[(q0 + r) * 65 + c] * ldsInv[q0 + r];
      vp[r] = val; s1 += val; s2 += val * val;
    }
    *(float4*)(y0 + ((size_t)(b * 64 + c) << 12) + qb0 + q0) = v4;
    s1 += __shfl_xor(s1, 1, 64);
    s2 += __shfl_xor(s2, 1, 64);
    s1 += __shfl_xor(s1, 2, 64);
    s2 += __shfl_xor(s2, 2, 64);
    s1 += __shfl_xor(s1, 4, 64);
    s2 += __shfl_xor(s2, 4, 64);
    if ((tid & 7) == 0) {
      atomicAdd(&gs1[c], s1);
      atomicAdd(&gs2[c], s2);
    }
  }
}

// ---------------------------------------------------------------------------
// apply: BN(scale/shift from gs1/gs2) + residual.
// ---------------------------------------------------------------------------
__global__ __launch_bounds__(256, 2) void pam_apply(
    const float* __restrict__ y0, const float* __restrict__ x,
    const float* __restrict__ gs1, const float* __restrict__ gs2,
    const float* __restrict__ bnw, const float* __restrict__ bnb,
    float* __restrict__ out)
{
  const int i = (blockIdx.x * 256 + threadIdx.x) << 2;   // 4 elems/thread
  const int c = (i >> 12) & 63;
  const float inv_n = 1.f / 16384.f;
  const float mean = gs1[c] * inv_n;
  const float var = fmaxf(gs2[c] * inv_n - mean * mean, 0.f);
  const float sc = bnw[c] * rsqrtf(var + 1e-5f);
  const float sh = bnb[c] - mean * sc;
  const float4 y = *(const float4*)(y0 + i);
  const float4 xv = *(const float4*)(x + i);
  float4 r;
  r.x = y.x * sc + sh + xv.x;
  r.y = y.y * sc + sh + xv.y;
  r.z = y.z * sc + sh + xv.z;
  r.w = y.w * sc + sh + xv.w;
  *(float4*)(out + i) = r;
}

// ---------------------------------------------------------------------------
extern "C" void kernel_launch(void* const* d_in, const int* in_sizes, int n_in,
                              void* d_out, int out_size, void* d_ws, size_t ws_size,
                              hipStream_t stream)
{
  (void)in_sizes; (void)n_in; (void)out_size; (void)ws_size;
  const float* x   = (const float*)d_in[0];
  const float* qw  = (const float*)d_in[1];
  const float* kw  = (const float*)d_in[2];
  const float* vw  = (const float*)d_in[3];
  const float* vb  = (const float*)d_in[4];
  const float* gam = (const float*)d_in[5];
  const float* bnw = (const float*)d_in[6];
  const float* bnb = (const float*)d_in[7];

  char* ws = (char*)d_ws;
  f16*   qa  = (f16*)(ws);
  f16*   ka2 = (f16*)(ws + (2u << 20));
  f16*   va3 = (f16*)(ws + (4u << 20));
  float* y0  = (float*)(ws + (6u << 20));
  float* gs1 = (float*)(ws + (10u << 20));          // 64 floats
  float* gs2 = (float*)(ws + (10u << 20) + 256);    // 64 floats (contiguous)

  pam_pre  <<<1024, 256, 0, stream>>>(x, qw, kw, vw, vb, qa, ka2, va3, gs1);
  pam_attn <<<512, 512, 0, stream>>>(qa, ka2, va3, gam, y0, gs1, gs2);
  pam_apply<<<1024, 256, 0, stream>>>(y0, x, gs1, gs2, bnw, bnb, (float*)d_out);
}